// Round 12
// baseline (186.087 us; speedup 1.0000x reference)
//
#include <hip/hip_runtime.h>

#define Nn 100000
#define Tt 16
#define Dd 8
#define Hh 40
#define HP1 41

// ---- pair-symmetric slab: i<=j<50 pairs x 16 t ----
#define NPAIR 1275
#define PSZ (NPAIR * 16)       // 20400 floats per slab

// ---- workspace layout (float slots) ----
#define XEH_OFF  0                     // XeHi [64][Nn] f16 -> 32*Nn float slots
#define XEL_OFF  (XEH_OFF + 32 * Nn)   // XeLo [64][Nn] f16
#define PHIT_OFF (XEL_OFF + 32 * Nn)   // PhiT [16][Nn] f32
#define PART_OFF (PHIT_OFF + 16 * Nn)  // 8 * PSZ partials
#define P_OFF    (PART_OFF + 8 * PSZ)  // slabs

// output offsets (flat, return order)
#define OFF_BG1   0
#define OFF_BG2   16
#define OFF_MU    32
#define OFF_KAPPA 160
#define OFF_NU    176
#define OFF_PSI   192
#define OFF_WM    1216
#define OFF_WS    1872
#define OFF_ZA    28768
#define OFF_ZB    28784
#define OFF_EA    28800
#define OFF_EB    28816

typedef _Float16 f16x8 __attribute__((ext_vector_type(8)));
typedef float f32x4 __attribute__((ext_vector_type(4)));
typedef unsigned int u32x4 __attribute__((ext_vector_type(4)));

__device__ __forceinline__ int pidx(int i, int j) {
  if (i > j) { int tmp = i; i = j; j = tmp; }
  return (i * (2 * 50 - i + 1)) / 2 + (j - i);
}

// ---------------- Kernel 0: ELM expansion -> XeHi/XeLo planes + PhiT ------
// Xe row layout c: [h0..h39, 1, x0..x7, y, 0...0] (c=50..63 zero)
__global__ __launch_bounds__(256)
void elm_expand(const float* __restrict__ Phi, const float* __restrict__ Xd,
                const float* __restrict__ Yd, const float* __restrict__ W,
                const float* __restrict__ bb,
                unsigned short* __restrict__ XeHi, unsigned short* __restrict__ XeLo,
                float* __restrict__ PhiT)
{
  __shared__ float sW[Dd * Hh];
  __shared__ float sb[Hh];
  __shared__ float xs[64][9];
  __shared__ float ys[64];
  __shared__ float hrow[64][41];
  __shared__ float pt[16][68];
  int tid = threadIdx.x;
  int n0 = blockIdx.x * 64;

  for (int i = tid; i < Dd * Hh; i += 256) sW[i] = W[i];
  if (tid < Hh) sb[tid] = bb[tid];
  if (tid < 128) {
    int nl = tid >> 1, h4 = (tid & 1) * 4;
    int gn = n0 + nl;
    float4 v = (gn < Nn) ? *(const float4*)(Xd + (size_t)gn * 8 + h4)
                         : make_float4(0.f, 0.f, 0.f, 0.f);
    xs[nl][h4 + 0] = v.x; xs[nl][h4 + 1] = v.y;
    xs[nl][h4 + 2] = v.z; xs[nl][h4 + 3] = v.w;
  }
  if (tid < 64) { int gn = n0 + tid; ys[tid] = (gn < Nn) ? Yd[gn] : 0.f; }
  {
    int nl = tid >> 2, q = tid & 3;
    int gn = n0 + nl;
    float4 v = (gn < Nn) ? *(const float4*)(Phi + (size_t)gn * 16 + q * 4)
                         : make_float4(0.f, 0.f, 0.f, 0.f);
    pt[q * 4 + 0][nl] = v.x; pt[q * 4 + 1][nl] = v.y;
    pt[q * 4 + 2][nl] = v.z; pt[q * 4 + 3][nl] = v.w;
  }
  __syncthreads();
  // sigmoids: thread -> (n, 10 h's)
  {
    int nl = tid >> 2, hq = (tid & 3) * 10;
    for (int hh = 0; hh < 10; ++hh) {
      int h = hq + hh;
      float z = sb[h];
#pragma unroll
      for (int d = 0; d < 8; ++d) z = fmaf(xs[nl][d], sW[d * Hh + h], z);
      hrow[nl][h] = 1.f / (1.f + __expf(-z));
    }
  }
  __syncthreads();
  // PhiT write: thread (t = tid&15, nq = tid>>4) -> float4
  {
    int t = tid & 15, nq = tid >> 4;
    int gn = n0 + nq * 4;
    if (gn < Nn) {
      float4 v = make_float4(pt[t][nq * 4 + 0], pt[t][nq * 4 + 1],
                             pt[t][nq * 4 + 2], pt[t][nq * 4 + 3]);
      *(float4*)(PhiT + (size_t)t * Nn + gn) = v;
    }
  }
  // Xe hi/lo planes: thread (c = tid>>2, seg = tid&3) covers 16 n's
  {
    int cidx = tid >> 2, seg = tid & 3;
    int nl0 = seg * 16;
    float vv[16];
#pragma unroll
    for (int j = 0; j < 16; ++j) {
      int n = nl0 + j;
      float v;
      if (cidx < Hh) v = hrow[n][cidx];
      else if (cidx == 40) v = 1.f;
      else if (cidx < 49) v = xs[n][cidx - 41];
      else if (cidx == 49) v = ys[n];
      else v = 0.f;
      vv[j] = v;
    }
    unsigned short hs[16], ls[16];
#pragma unroll
    for (int j = 0; j < 16; ++j) {
      _Float16 h = (_Float16)vv[j];
      float r = vv[j] - (float)h;
      _Float16 lo = (_Float16)r;
      hs[j] = __builtin_bit_cast(unsigned short, h);
      ls[j] = __builtin_bit_cast(unsigned short, lo);
    }
#pragma unroll
    for (int q2 = 0; q2 < 2; ++q2) {
      int gn = n0 + nl0 + q2 * 8;
      if (gn < Nn) {
        uint4 uh, ul;
        uh.x = hs[q2*8+0] | ((unsigned)hs[q2*8+1] << 16);
        uh.y = hs[q2*8+2] | ((unsigned)hs[q2*8+3] << 16);
        uh.z = hs[q2*8+4] | ((unsigned)hs[q2*8+5] << 16);
        uh.w = hs[q2*8+6] | ((unsigned)hs[q2*8+7] << 16);
        ul.x = ls[q2*8+0] | ((unsigned)ls[q2*8+1] << 16);
        ul.y = ls[q2*8+2] | ((unsigned)ls[q2*8+3] << 16);
        ul.z = ls[q2*8+4] | ((unsigned)ls[q2*8+5] << 16);
        ul.w = ls[q2*8+6] | ((unsigned)ls[q2*8+7] << 16);
        *(uint4*)(XeHi + (size_t)cidx * Nn + gn) = uh;
        *(uint4*)(XeLo + (size_t)cidx * Nn + gn) = ul;
      }
    }
  }
}

// ---------------- Kernel 1: MFMA Gram, 512-thr block = whole chunk ----------------
// One block per K-chunk (measured-best R4 structure). 8 waves cover all 52 i-rows
// (4x7 + 4x6 M-tiles). A rows are a SUBSET of B rows: the staged B hi/lo planes
// serve both operands. LDS per buffer (10KB): Bhi[64 rows][32k]f16 @0, Blo @4096,
// phi f32[16][32k] @8192. 2-buffer ring, one __syncthreads per step (compiler's
// own vmcnt handling — measured faster than explicit counted-vmcnt variants).
// Swizzle (FIX vs R4): B/A granule' = g ^ ((row>>1)&3) — balances b128 reads to
// the 8-dword/bank LDS floor (old (row&3) left 16 dwords/bank = 2x). phi:
// granule' = g ^ (row&7). Applied on pre-swizzled global source (linear LDS
// dest, m173 pattern) and identically on every ds_read.
__device__ __forceinline__ void gload16(const void* g, void* l) {
  __builtin_amdgcn_global_load_lds(
      (const __attribute__((address_space(1))) unsigned int*)g,
      (__attribute__((address_space(3))) unsigned int*)l, 16, 0, 0);
}

__global__ __launch_bounds__(512, 2)
void gram_mfma(const float* __restrict__ PhiT,
               const unsigned short* __restrict__ XeHi,
               const unsigned short* __restrict__ XeLo,
               float* __restrict__ P, int CH)
{
  __shared__ __align__(16) char smem[2][10240];

  int tid = threadIdx.x;
  int c = blockIdx.x;
  int l = tid & 63, w = tid >> 6;
  int l15 = l & 15, lg = l >> 4;
  int n0 = c * CH;
  int rem = Nn - n0; if (rem > CH) rem = CH;
  int nsteps = rem >> 5;

  // per-wave M-tile range: waves 0-3 own 7 tiles, 4-7 own 6 (total 52)
  int MT  = (w < 4) ? 7 : 6;
  int i0w = (w < 4) ? 7 * w : 28 + 6 * (w - 4);

  // ---- staging decode: 512 B granules (1/thread) + 128 phi granules ----
  const char* g0; const char* g1 = nullptr;
  int ld0 = tid * 16, ld1 = (512 + tid) * 16;
  {
    int r = (tid & 255) >> 2, s = tid & 3;
    const unsigned short* bp = (tid < 256) ? XeHi : XeLo;
    g0 = (const char*)(bp + (size_t)r * Nn + n0 + 8 * (s ^ ((r >> 1) & 3)));
    if (tid < 128) {
      int t = tid >> 3, s2 = tid & 7;
      g1 = (const char*)(PhiT + (size_t)t * Nn + n0 + 4 * (s2 ^ (t & 7)));
    }
  }

#define STAGE(buf) do {                              \
    char* db = &smem[buf][0];                        \
    gload16(g0, db + ld0); g0 += 64;                 \
    if (tid < 128) { gload16(g1, db + ld1); g1 += 128; } \
  } while (0)

  // ---- read offsets (bytes) ----
  int off_b[4];
#pragma unroll
  for (int nt = 0; nt < 4; ++nt) {
    int j = l15 + 16 * nt;
    off_b[nt] = j * 64 + 16 * (lg ^ ((j >> 1) & 3));
  }
  int off_p0 = 8192 + l15 * 128 + 16 * ((2 * lg) ^ (l15 & 7));
  int off_p1 = 8192 + l15 * 128 + 16 * ((2 * lg + 1) ^ (l15 & 7));
  int off_a[7];
#pragma unroll
  for (int mi = 0; mi < 7; ++mi) {
    int i = i0w + mi;              // <= 52; rows >= 50 are exact zeros
    off_a[mi] = i * 64 + 16 * (lg ^ ((i >> 1) & 3));
  }

  f32x4 acc[7][4];
#pragma unroll
  for (int mi = 0; mi < 7; ++mi)
#pragma unroll
    for (int nt = 0; nt < 4; ++nt) acc[mi][nt] = (f32x4){0.f, 0.f, 0.f, 0.f};

  STAGE(0);
  __syncthreads();

  for (int s = 0; s < nsteps; ++s) {
    int cur = s & 1;
    if (s + 1 < nsteps) STAGE(cur ^ 1);

    const char* base = &smem[cur][0];
    f32x4 p0 = *(const f32x4*)(base + off_p0);
    f32x4 p1 = *(const f32x4*)(base + off_p1);
    float ph[8] = {p0[0], p0[1], p0[2], p0[3], p1[0], p1[1], p1[2], p1[3]};

    f16x8 bh[4], bl[4];
#pragma unroll
    for (int nt = 0; nt < 4; ++nt) {
      bh[nt] = *(const f16x8*)(base + off_b[nt]);
      bl[nt] = *(const f16x8*)(base + 4096 + off_b[nt]);
    }
    __builtin_amdgcn_s_setprio(1);
#pragma unroll
    for (int mi = 0; mi < 7; ++mi) {
      if (mi >= MT) break;
      f16x8 xh = *(const f16x8*)(base + off_a[mi]);          // broadcast
      f16x8 xl = *(const f16x8*)(base + 4096 + off_a[mi]);   // broadcast
      float v0 = ph[0] * ((float)xh[0] + (float)xl[0]);
      float v1 = ph[1] * ((float)xh[1] + (float)xl[1]);
      float v2 = ph[2] * ((float)xh[2] + (float)xl[2]);
      float v3 = ph[3] * ((float)xh[3] + (float)xl[3]);
      float v4 = ph[4] * ((float)xh[4] + (float)xl[4]);
      float v5 = ph[5] * ((float)xh[5] + (float)xl[5]);
      float v6 = ph[6] * ((float)xh[6] + (float)xl[6]);
      float v7 = ph[7] * ((float)xh[7] + (float)xl[7]);
      auto h0 = __builtin_amdgcn_cvt_pkrtz(v0, v1);
      auto h1 = __builtin_amdgcn_cvt_pkrtz(v2, v3);
      auto h2 = __builtin_amdgcn_cvt_pkrtz(v4, v5);
      auto h3 = __builtin_amdgcn_cvt_pkrtz(v6, v7);
      float r0 = v0 - (float)h0[0], r1 = v1 - (float)h0[1];
      float r2 = v2 - (float)h1[0], r3 = v3 - (float)h1[1];
      float r4 = v4 - (float)h2[0], r5 = v5 - (float)h2[1];
      float r6 = v6 - (float)h3[0], r7 = v7 - (float)h3[1];
      auto e0 = __builtin_amdgcn_cvt_pkrtz(r0, r1);
      auto e1 = __builtin_amdgcn_cvt_pkrtz(r2, r3);
      auto e2 = __builtin_amdgcn_cvt_pkrtz(r4, r5);
      auto e3 = __builtin_amdgcn_cvt_pkrtz(r6, r7);
      u32x4 uh = {__builtin_bit_cast(unsigned int, h0), __builtin_bit_cast(unsigned int, h1),
                  __builtin_bit_cast(unsigned int, h2), __builtin_bit_cast(unsigned int, h3)};
      u32x4 ul = {__builtin_bit_cast(unsigned int, e0), __builtin_bit_cast(unsigned int, e1),
                  __builtin_bit_cast(unsigned int, e2), __builtin_bit_cast(unsigned int, e3)};
      f16x8 ah = __builtin_bit_cast(f16x8, uh);
      f16x8 al = __builtin_bit_cast(f16x8, ul);
#pragma unroll
      for (int nt = 0; nt < 4; ++nt) {
        acc[mi][nt] = __builtin_amdgcn_mfma_f32_16x16x32_f16(ah, bh[nt], acc[mi][nt], 0, 0, 0);
        acc[mi][nt] = __builtin_amdgcn_mfma_f32_16x16x32_f16(ah, bl[nt], acc[mi][nt], 0, 0, 0);
        acc[mi][nt] = __builtin_amdgcn_mfma_f32_16x16x32_f16(al, bh[nt], acc[mi][nt], 0, 0, 0);
      }
    }
    __builtin_amdgcn_s_setprio(0);
    __syncthreads();
  }
#undef STAGE

  // epilogue: pair-symmetric slab write (i<=j<50), f32x4 over t = lg*4+r
  float* Pc = P + (size_t)c * PSZ;
#pragma unroll
  for (int mi = 0; mi < 7; ++mi) {
    if (mi >= MT) break;
    int i = i0w + mi;
    if (i < 50) {
#pragma unroll
      for (int nt = 0; nt < 4; ++nt) {
        int j = nt * 16 + l15;
        if (j >= i && j < 50) {
          int pb = (i * (101 - i)) / 2 + (j - i);
          *(f32x4*)(Pc + pb * 16 + lg * 4) = acc[mi][nt];
        }
      }
    }
  }
}

// ---------------- Kernel 2: slab reduction (nslabs -> 8 groups) ----------------
__global__ __launch_bounds__(256)
void reduce_a(const float4* __restrict__ P4, int nslabs, float4* __restrict__ part4)
{
  int g = blockIdx.y;                               // 0..7
  int idx = blockIdx.x * 256 + threadIdx.x;         // 20 blocks cover PSZ/4 = 5100
  if (idx >= PSZ / 4) return;
  int per = (nslabs + 7) / 8;
  int c0 = g * per, c1 = c0 + per; if (c1 > nslabs) c1 = nslabs;
  float4 s = make_float4(0.f, 0.f, 0.f, 0.f);
  for (int cc = c0; cc < c1; ++cc) {
    float4 v = P4[(size_t)cc * (PSZ / 4) + idx];
    s.x += v.x; s.y += v.y; s.z += v.z; s.w += v.w;
  }
  part4[(size_t)g * (PSZ / 4) + idx] = s;
}

// ---------------- Kernel 3: finalize (GJ inverse etc.), sums 8 partials inline ------
__device__ __forceinline__ float accv(const float* __restrict__ part, int idx) {
  float s = 0.f;
#pragma unroll
  for (int g = 0; g < 8; ++g) s += part[g * PSZ + idx];
  return s;
}

__global__ __launch_bounds__(256)
void finalize_kernel(const float* __restrict__ part, const float* __restrict__ epsA,
                     const float* __restrict__ epsB, const float* __restrict__ zetA,
                     const float* __restrict__ zetB, float* __restrict__ out)
{
  int t = blockIdx.x;
  int tid = threadIdx.x;
  __shared__ float G[HP1][84];          // [M | I] augmented
  __shared__ float As[HP1][HP1 + 1];
  __shared__ float bs[HP1];
  __shared__ float colk[HP1];
  __shared__ float red[256];
  __shared__ float wmv[HP1];
  __shared__ float rowv[4][HP1 + 1];
  __shared__ float mus[Dd];

  float epsExp = epsA[t] / epsB[t];
  float zetaExp = zetA[t] / zetB[t];

  for (int idx = tid; idx < HP1 * HP1; idx += 256) {
    int i = idx / HP1, j = idx % HP1;
    float a = accv(part, pidx(i, j) * Tt + t);
    As[i][j] = a;
    G[i][j] = epsExp * a + (i == j ? zetaExp : 0.f);
    G[i][41 + j] = (i == j) ? 1.f : 0.f;
  }
  for (int idx = tid; idx < HP1; idx += 256) {
    G[idx][82] = 0.f; G[idx][83] = 0.f;
    bs[idx] = accv(part, pidx(idx, 49) * Tt + t);
  }
  __syncthreads();

  int c = tid % HP1;         // 0..40
  int ig = tid / HP1;        // 0..6; ig<6 active
  int irow0 = ig * 7;

  for (int k = 0; k < HP1; ++k) {
    float pivinv = 1.f / G[k][k];
    if (tid >= 1 && tid <= HP1) G[k][k + tid] *= pivinv;
    if (tid < HP1) colk[tid] = (tid == k) ? 0.f : G[tid][k];
    __syncthreads();
    if (ig < 6) {
      int j = k + 1 + c;
      float pk = G[k][j];
#pragma unroll
      for (int r = 0; r < 7; ++r) {
        int i = irow0 + r;
        if (i < HP1 && i != k) G[i][j] = fmaf(-colk[i], pk, G[i][j]);
      }
    }
    __syncthreads();
  }

  for (int idx = tid; idx < HP1 * HP1; idx += 256) {
    int i = idx / HP1, j = idx % HP1;
    out[OFF_WS + (t * HP1 + i) * HP1 + j] = G[i][41 + j];
  }
  if (tid < HP1) {
    float s = 0.f;
    for (int j = 0; j < HP1; ++j) s += G[tid][41 + j] * bs[j];
    float w = zetaExp * s;
    wmv[tid] = w;
    out[OFF_WM + t * HP1 + tid] = w;
  }
  __syncthreads();
  float lt2 = 0.f;
  for (int idx = tid; idx < HP1 * HP1; idx += 256) {
    int i = idx / HP1, j = idx % HP1;
    lt2 += As[i][j] * G[i][41 + j];
  }
  red[tid] = lt2; __syncthreads();
  for (int s = 128; s > 0; s >>= 1) {
    if (tid < s) red[tid] += red[tid + s];
    __syncthreads();
  }
  float t2v = red[0];
  if (tid < HP1) {
    float w = wmv[tid];
    float aw = 0.f;
    for (int j = 0; j < HP1; ++j) aw += As[tid][j] * wmv[j];
    rowv[0][tid] = w * bs[tid];
    rowv[1][tid] = w * w;
    rowv[2][tid] = G[tid][41 + tid];
    rowv[3][tid] = w * aw;
  }
  __syncthreads();

  float sp = accv(part, pidx(40, 40) * Tt + t);
  float kap = 1000.f + sp;
  float syy = accv(part, pidx(49, 49) * Tt + t);

  if (tid == 0) {
    float wb = 0.f, wn = 0.f, trc = 0.f, quad = 0.f;
    for (int i = 0; i < HP1; ++i) {
      wb += rowv[0][i]; wn += rowv[1][i]; trc += rowv[2][i]; quad += rowv[3][i];
    }
    float t1 = syy - 2.f * wb + quad;
    out[OFF_BG1 + t] = 1.f + sp;
    float rest = 0.f;
    for (int u = t + 1; u < Tt; ++u) rest += accv(part, pidx(40, 40) * Tt + u);
    out[OFF_BG2 + t] = 1.f + rest;            // ALPHA_DP = 1
    out[OFF_KAPPA + t] = kap;
    out[OFF_NU + t] = sp + 100.f;
    out[OFF_ZA + t] = zetA[t] + 0.5f * (float)HP1;
    out[OFF_ZB + t] = zetB[t] + 0.5f * (wn + trc);
    out[OFF_EA + t] = epsA[t] + 0.5f * sp;
    out[OFF_EB + t] = epsB[t] + 0.5f * (t1 + t2v);
  }
  if (tid < Dd) {
    float m = accv(part, pidx(40, 41 + tid) * Tt + t) / kap;
    mus[tid] = m;
    out[OFF_MU + tid * Tt + t] = m;
  }
  __syncthreads();
  if (tid < Dd * Dd) {
    int i = tid / Dd, j = tid % Dd;
    float S = accv(part, pidx(41 + i, 41 + j) * Tt + t);
    float v = (i == j ? 500.f : 0.f) + S - kap * mus[i] * mus[j];
    out[OFF_PSI + (i * Dd + j) * Tt + t] = v;
  }
}

extern "C" void kernel_launch(void* const* d_in, const int* in_sizes, int n_in,
                              void* d_out, int out_size, void* d_ws, size_t ws_size,
                              hipStream_t stream) {
  const float* Phi = (const float*)d_in[1];
  const float* Xd  = (const float*)d_in[2];
  const float* Yd  = (const float*)d_in[3];
  const float* W   = (const float*)d_in[4];
  const float* bb  = (const float*)d_in[5];
  const float* eA  = (const float*)d_in[6];
  const float* eB  = (const float*)d_in[7];
  const float* zA  = (const float*)d_in[8];
  const float* zB  = (const float*)d_in[9];
  float* out = (float*)d_out;
  float* ws  = (float*)d_ws;

  unsigned short* XeHi = (unsigned short*)(ws + XEH_OFF);
  unsigned short* XeLo = (unsigned short*)(ws + XEL_OFF);
  float* PhiT = ws + PHIT_OFF;
  float* part = ws + PART_OFF;
  float* P    = ws + P_OFF;

  // adapt chunk count to workspace (deterministic, graph-safe).
  // target 391 chunks of 256 n (8 steps) -> 135 CUs hold 2 desynced blocks.
  long maxChunks = ((long)(ws_size / 4) - (long)P_OFF) / PSZ;
  if (maxChunks < 1) maxChunks = 1;
  long cap = maxChunks < 391 ? maxChunks : 391;
  long sp = (3125 + cap - 1) / cap;    // 32-k steps per chunk (8 when cap=391)
  int CH = (int)(32 * sp);
  int KCe = (Nn + CH - 1) / CH;

  hipLaunchKernelGGL(elm_expand, dim3((Nn + 63) / 64), dim3(256), 0, stream,
                     Phi, Xd, Yd, W, bb, XeHi, XeLo, PhiT);
  hipLaunchKernelGGL(gram_mfma, dim3(KCe), dim3(512), 0, stream,
                     PhiT, XeHi, XeLo, P, CH);
  hipLaunchKernelGGL(reduce_a, dim3(20, 8), dim3(256), 0, stream,
                     (const float4*)P, KCe, (float4*)part);
  hipLaunchKernelGGL(finalize_kernel, dim3(Tt), dim3(256), 0, stream,
                     part, eA, eB, zA, zB, out);
}

// Round 13
// 171.030 us; speedup vs baseline: 1.0880x; 1.0880x over previous
//
#include <hip/hip_runtime.h>

#define Nn 100000
#define Tt 16
#define Dd 8
#define Hh 40
#define HP1 41

// ---- workspace layout (float slots) ----
#define CSZ 53248                      // 52*16*64 floats per chunk-partial
#define XEH_OFF  0                     // XeHi [64][Nn] f16 -> 32*Nn float slots
#define XEL_OFF  (XEH_OFF + 32 * Nn)   // XeLo [64][Nn] f16
#define PHIT_OFF (XEL_OFF + 32 * Nn)   // PhiT [16][Nn] f32
#define PART_OFF (PHIT_OFF + 16 * Nn)  // 8 * CSZ partials
#define P_OFF    (PART_OFF + 8 * CSZ)  // chunk partials

// output offsets (flat, return order)
#define OFF_BG1   0
#define OFF_BG2   16
#define OFF_MU    32
#define OFF_KAPPA 160
#define OFF_NU    176
#define OFF_PSI   192
#define OFF_WM    1216
#define OFF_WS    1872
#define OFF_ZA    28768
#define OFF_ZB    28784
#define OFF_EA    28800
#define OFF_EB    28816

typedef _Float16 f16x8 __attribute__((ext_vector_type(8)));
typedef float f32x4 __attribute__((ext_vector_type(4)));
typedef unsigned int u32x4 __attribute__((ext_vector_type(4)));

// A-index into partials: value A[t][i][j] at ((i*16+t)*64)+j
#define AIDX(i, t, j) ((((i) * 16 + (t)) * 64) + (j))

// ---------------- Kernel 0: ELM expansion -> XeHi/XeLo planes + PhiT ------
// Xe row layout c: [h0..h39, 1, x0..x7, y, 0...0] (c=50..63 zero)
__global__ __launch_bounds__(256)
void elm_expand(const float* __restrict__ Phi, const float* __restrict__ Xd,
                const float* __restrict__ Yd, const float* __restrict__ W,
                const float* __restrict__ bb,
                unsigned short* __restrict__ XeHi, unsigned short* __restrict__ XeLo,
                float* __restrict__ PhiT)
{
  __shared__ float sW[Dd * Hh];
  __shared__ float sb[Hh];
  __shared__ float xs[64][9];
  __shared__ float ys[64];
  __shared__ float hrow[64][41];
  __shared__ float pt[16][68];
  int tid = threadIdx.x;
  int n0 = blockIdx.x * 64;

  for (int i = tid; i < Dd * Hh; i += 256) sW[i] = W[i];
  if (tid < Hh) sb[tid] = bb[tid];
  if (tid < 128) {
    int nl = tid >> 1, h4 = (tid & 1) * 4;
    int gn = n0 + nl;
    float4 v = (gn < Nn) ? *(const float4*)(Xd + (size_t)gn * 8 + h4)
                         : make_float4(0.f, 0.f, 0.f, 0.f);
    xs[nl][h4 + 0] = v.x; xs[nl][h4 + 1] = v.y;
    xs[nl][h4 + 2] = v.z; xs[nl][h4 + 3] = v.w;
  }
  if (tid < 64) { int gn = n0 + tid; ys[tid] = (gn < Nn) ? Yd[gn] : 0.f; }
  {
    int nl = tid >> 2, q = tid & 3;
    int gn = n0 + nl;
    float4 v = (gn < Nn) ? *(const float4*)(Phi + (size_t)gn * 16 + q * 4)
                         : make_float4(0.f, 0.f, 0.f, 0.f);
    pt[q * 4 + 0][nl] = v.x; pt[q * 4 + 1][nl] = v.y;
    pt[q * 4 + 2][nl] = v.z; pt[q * 4 + 3][nl] = v.w;
  }
  __syncthreads();
  // sigmoids: thread -> (n, 10 h's)
  {
    int nl = tid >> 2, hq = (tid & 3) * 10;
    for (int hh = 0; hh < 10; ++hh) {
      int h = hq + hh;
      float z = sb[h];
#pragma unroll
      for (int d = 0; d < 8; ++d) z = fmaf(xs[nl][d], sW[d * Hh + h], z);
      hrow[nl][h] = 1.f / (1.f + __expf(-z));
    }
  }
  __syncthreads();
  // PhiT write: thread (t = tid&15, nq = tid>>4) -> float4
  {
    int t = tid & 15, nq = tid >> 4;
    int gn = n0 + nq * 4;
    if (gn < Nn) {
      float4 v = make_float4(pt[t][nq * 4 + 0], pt[t][nq * 4 + 1],
                             pt[t][nq * 4 + 2], pt[t][nq * 4 + 3]);
      *(float4*)(PhiT + (size_t)t * Nn + gn) = v;
    }
  }
  // Xe hi/lo planes: thread (c = tid>>2, seg = tid&3) covers 16 n's
  {
    int cidx = tid >> 2, seg = tid & 3;
    int nl0 = seg * 16;
    float vv[16];
#pragma unroll
    for (int j = 0; j < 16; ++j) {
      int n = nl0 + j;
      float v;
      if (cidx < Hh) v = hrow[n][cidx];
      else if (cidx == 40) v = 1.f;
      else if (cidx < 49) v = xs[n][cidx - 41];
      else if (cidx == 49) v = ys[n];
      else v = 0.f;
      vv[j] = v;
    }
    unsigned short hs[16], ls[16];
#pragma unroll
    for (int j = 0; j < 16; ++j) {
      _Float16 h = (_Float16)vv[j];
      float r = vv[j] - (float)h;
      _Float16 lo = (_Float16)r;
      hs[j] = __builtin_bit_cast(unsigned short, h);
      ls[j] = __builtin_bit_cast(unsigned short, lo);
    }
#pragma unroll
    for (int q2 = 0; q2 < 2; ++q2) {
      int gn = n0 + nl0 + q2 * 8;
      if (gn < Nn) {
        uint4 uh, ul;
        uh.x = hs[q2*8+0] | ((unsigned)hs[q2*8+1] << 16);
        uh.y = hs[q2*8+2] | ((unsigned)hs[q2*8+3] << 16);
        uh.z = hs[q2*8+4] | ((unsigned)hs[q2*8+5] << 16);
        uh.w = hs[q2*8+6] | ((unsigned)hs[q2*8+7] << 16);
        ul.x = ls[q2*8+0] | ((unsigned)ls[q2*8+1] << 16);
        ul.y = ls[q2*8+2] | ((unsigned)ls[q2*8+3] << 16);
        ul.z = ls[q2*8+4] | ((unsigned)ls[q2*8+5] << 16);
        ul.w = ls[q2*8+6] | ((unsigned)ls[q2*8+7] << 16);
        *(uint4*)(XeHi + (size_t)cidx * Nn + gn) = uh;
        *(uint4*)(XeLo + (size_t)cidx * Nn + gn) = ul;
      }
    }
  }
}

// ---------------- Kernel 1: MFMA Gram, 512-thr block = whole chunk ----------------
// Measured-best structure (R4 = 170.6 us total) + ONE change: the LDS swizzle is
// swz(row) = (row>>1)&3 (was row&3), which balances ds_read_b128 to exact 2-way
// bank aliasing (free, m136) — verified 1.0M -> 200K conflict cycles in R12.
// One block per K-chunk. 8 waves cover all 52 i-rows (4x7 + 4x6 M-tiles).
// A rows are a SUBSET of B rows: the staged B hi/lo planes serve both operands.
// LDS per buffer (10KB): Bhi[64 rows][32k]f16 @0, Blo @4096, phi f32[16][32k] @8192.
// 2-buffer ring, one __syncthreads per step (compiler's own vmcnt scheduling —
// measured faster than every explicit counted-vmcnt variant this session).
// phi stage runs under a WAVE-UNIFORM tid<128 branch (safe for global_load_lds;
// lane-divergent exec is the R10-verified corruption mode).
__device__ __forceinline__ void gload16(const void* g, void* l) {
  __builtin_amdgcn_global_load_lds(
      (const __attribute__((address_space(1))) unsigned int*)g,
      (__attribute__((address_space(3))) unsigned int*)l, 16, 0, 0);
}

__global__ __launch_bounds__(512, 2)
void gram_mfma(const float* __restrict__ PhiT,
               const unsigned short* __restrict__ XeHi,
               const unsigned short* __restrict__ XeLo,
               float* __restrict__ P, int CH)
{
  __shared__ __align__(16) char smem[2][10240];

  int tid = threadIdx.x;
  int c = blockIdx.x;
  int l = tid & 63, w = tid >> 6;
  int l15 = l & 15, lg = l >> 4;
  int n0 = c * CH;
  int rem = Nn - n0; if (rem > CH) rem = CH;
  int nsteps = rem >> 5;

  // per-wave M-tile range: waves 0-3 own 7 tiles, 4-7 own 6 (total 52)
  int MT  = (w < 4) ? 7 : 6;
  int i0w = (w < 4) ? 7 * w : 28 + 6 * (w - 4);

  // ---- staging decode: 512 B granules (1/thread) + 128 phi granules ----
  const char* g0; const char* g1 = nullptr;
  int ld0 = tid * 16, ld1 = (512 + tid) * 16;
  {
    int r = (tid & 255) >> 2, s = tid & 3;
    const unsigned short* bp = (tid < 256) ? XeHi : XeLo;
    g0 = (const char*)(bp + (size_t)r * Nn + n0 + 8 * (s ^ ((r >> 1) & 3)));
    if (tid < 128) {
      int t = tid >> 3, s2 = tid & 7;
      g1 = (const char*)(PhiT + (size_t)t * Nn + n0 + 4 * (s2 ^ (t & 7)));
    }
  }

#define STAGE(buf) do {                              \
    char* db = &smem[buf][0];                        \
    gload16(g0, db + ld0); g0 += 64;                 \
    if (tid < 128) { gload16(g1, db + ld1); g1 += 128; } \
  } while (0)

  // ---- read offsets (bytes) ----
  int off_b[4];
#pragma unroll
  for (int nt = 0; nt < 4; ++nt) {
    int j = l15 + 16 * nt;
    off_b[nt] = j * 64 + 16 * (lg ^ ((j >> 1) & 3));
  }
  int off_p0 = 8192 + l15 * 128 + 16 * ((2 * lg) ^ (l15 & 7));
  int off_p1 = 8192 + l15 * 128 + 16 * ((2 * lg + 1) ^ (l15 & 7));
  int off_a[7];
#pragma unroll
  for (int mi = 0; mi < 7; ++mi) {
    int i = i0w + mi;              // <= 52; rows >= 50 are exact zeros
    off_a[mi] = i * 64 + 16 * (lg ^ ((i >> 1) & 3));
  }

  f32x4 acc[7][4];
#pragma unroll
  for (int mi = 0; mi < 7; ++mi)
#pragma unroll
    for (int nt = 0; nt < 4; ++nt) acc[mi][nt] = (f32x4){0.f, 0.f, 0.f, 0.f};

  STAGE(0);
  __syncthreads();

  for (int s = 0; s < nsteps; ++s) {
    int cur = s & 1;
    if (s + 1 < nsteps) STAGE(cur ^ 1);

    const char* base = &smem[cur][0];
    f32x4 p0 = *(const f32x4*)(base + off_p0);
    f32x4 p1 = *(const f32x4*)(base + off_p1);
    float ph[8] = {p0[0], p0[1], p0[2], p0[3], p1[0], p1[1], p1[2], p1[3]};

    f16x8 bh[4], bl[4];
#pragma unroll
    for (int nt = 0; nt < 4; ++nt) {
      bh[nt] = *(const f16x8*)(base + off_b[nt]);
      bl[nt] = *(const f16x8*)(base + 4096 + off_b[nt]);
    }
#pragma unroll
    for (int mi = 0; mi < 7; ++mi) {
      if (mi >= MT) break;
      f16x8 xh = *(const f16x8*)(base + off_a[mi]);          // broadcast
      f16x8 xl = *(const f16x8*)(base + 4096 + off_a[mi]);   // broadcast
      float v0 = ph[0] * ((float)xh[0] + (float)xl[0]);
      float v1 = ph[1] * ((float)xh[1] + (float)xl[1]);
      float v2 = ph[2] * ((float)xh[2] + (float)xl[2]);
      float v3 = ph[3] * ((float)xh[3] + (float)xl[3]);
      float v4 = ph[4] * ((float)xh[4] + (float)xl[4]);
      float v5 = ph[5] * ((float)xh[5] + (float)xl[5]);
      float v6 = ph[6] * ((float)xh[6] + (float)xl[6]);
      float v7 = ph[7] * ((float)xh[7] + (float)xl[7]);
      auto h0 = __builtin_amdgcn_cvt_pkrtz(v0, v1);
      auto h1 = __builtin_amdgcn_cvt_pkrtz(v2, v3);
      auto h2 = __builtin_amdgcn_cvt_pkrtz(v4, v5);
      auto h3 = __builtin_amdgcn_cvt_pkrtz(v6, v7);
      float r0 = v0 - (float)h0[0], r1 = v1 - (float)h0[1];
      float r2 = v2 - (float)h1[0], r3 = v3 - (float)h1[1];
      float r4 = v4 - (float)h2[0], r5 = v5 - (float)h2[1];
      float r6 = v6 - (float)h3[0], r7 = v7 - (float)h3[1];
      auto e0 = __builtin_amdgcn_cvt_pkrtz(r0, r1);
      auto e1 = __builtin_amdgcn_cvt_pkrtz(r2, r3);
      auto e2 = __builtin_amdgcn_cvt_pkrtz(r4, r5);
      auto e3 = __builtin_amdgcn_cvt_pkrtz(r6, r7);
      u32x4 uh = {__builtin_bit_cast(unsigned int, h0), __builtin_bit_cast(unsigned int, h1),
                  __builtin_bit_cast(unsigned int, h2), __builtin_bit_cast(unsigned int, h3)};
      u32x4 ul = {__builtin_bit_cast(unsigned int, e0), __builtin_bit_cast(unsigned int, e1),
                  __builtin_bit_cast(unsigned int, e2), __builtin_bit_cast(unsigned int, e3)};
      f16x8 ah = __builtin_bit_cast(f16x8, uh);
      f16x8 al = __builtin_bit_cast(f16x8, ul);
#pragma unroll
      for (int nt = 0; nt < 4; ++nt) {
        acc[mi][nt] = __builtin_amdgcn_mfma_f32_16x16x32_f16(ah, bh[nt], acc[mi][nt], 0, 0, 0);
        acc[mi][nt] = __builtin_amdgcn_mfma_f32_16x16x32_f16(ah, bl[nt], acc[mi][nt], 0, 0, 0);
        acc[mi][nt] = __builtin_amdgcn_mfma_f32_16x16x32_f16(al, bh[nt], acc[mi][nt], 0, 0, 0);
      }
    }
    __syncthreads();
  }
#undef STAGE

  // epilogue: C row = t = lg*4+r, col = j (verified C map)
  float* Pc = P + (size_t)c * CSZ;
#pragma unroll
  for (int mi = 0; mi < 7; ++mi) {
    if (mi >= MT) break;
    int i = i0w + mi;
#pragma unroll
    for (int nt = 0; nt < 4; ++nt) {
      int j = nt * 16 + l15;
#pragma unroll
      for (int r = 0; r < 4; ++r)
        Pc[(i * 16 + lg * 4 + r) * 64 + j] = acc[mi][nt][r];
    }
  }
}

// ---------------- Kernel 2: chunk-partial reduction (KCe -> 8 groups) ----------------
__global__ __launch_bounds__(256)
void reduce_a(const float4* __restrict__ P4, int nchunks, float4* __restrict__ part4)
{
  int g = blockIdx.y;                               // 0..7
  int idx = blockIdx.x * 256 + threadIdx.x;         // 52 blocks cover CSZ/4
  int per = (nchunks + 7) / 8;
  int c0 = g * per, c1 = c0 + per; if (c1 > nchunks) c1 = nchunks;
  float4 s = make_float4(0.f, 0.f, 0.f, 0.f);
  for (int cc = c0; cc < c1; ++cc) {
    float4 v = P4[(size_t)cc * (CSZ / 4) + idx];
    s.x += v.x; s.y += v.y; s.z += v.z; s.w += v.w;
  }
  part4[(size_t)g * (CSZ / 4) + idx] = s;
}

// ---------------- Kernel 3: finalize (GJ inverse etc.), sums 8 partials inline ------
__device__ __forceinline__ float accv(const float* __restrict__ part, int idx) {
  float s = 0.f;
#pragma unroll
  for (int g = 0; g < 8; ++g) s += part[g * CSZ + idx];
  return s;
}

__global__ __launch_bounds__(256)
void finalize_kernel(const float* __restrict__ part, const float* __restrict__ epsA,
                     const float* __restrict__ epsB, const float* __restrict__ zetA,
                     const float* __restrict__ zetB, float* __restrict__ out)
{
  int t = blockIdx.x;
  int tid = threadIdx.x;
  __shared__ float G[HP1][84];          // [M | I] augmented
  __shared__ float As[HP1][HP1 + 1];
  __shared__ float bs[HP1];
  __shared__ float colk[HP1];
  __shared__ float red[256];
  __shared__ float wmv[HP1];
  __shared__ float rowv[4][HP1 + 1];
  __shared__ float mus[Dd];

  float epsExp = epsA[t] / epsB[t];
  float zetaExp = zetA[t] / zetB[t];

  for (int idx = tid; idx < HP1 * HP1; idx += 256) {
    int i = idx / HP1, j = idx % HP1;
    float a = accv(part, AIDX(i, t, j));
    As[i][j] = a;
    G[i][j] = epsExp * a + (i == j ? zetaExp : 0.f);
    G[i][41 + j] = (i == j) ? 1.f : 0.f;
  }
  for (int idx = tid; idx < HP1; idx += 256) {
    G[idx][82] = 0.f; G[idx][83] = 0.f;
    bs[idx] = accv(part, AIDX(idx, t, 49));
  }
  __syncthreads();

  int c = tid % HP1;         // 0..40
  int ig = tid / HP1;        // 0..6; ig<6 active
  int irow0 = ig * 7;

  for (int k = 0; k < HP1; ++k) {
    float pivinv = 1.f / G[k][k];
    if (tid >= 1 && tid <= HP1) G[k][k + tid] *= pivinv;
    if (tid < HP1) colk[tid] = (tid == k) ? 0.f : G[tid][k];
    __syncthreads();
    if (ig < 6) {
      int j = k + 1 + c;
      float pk = G[k][j];
#pragma unroll
      for (int r = 0; r < 7; ++r) {
        int i = irow0 + r;
        if (i < HP1 && i != k) G[i][j] = fmaf(-colk[i], pk, G[i][j]);
      }
    }
    __syncthreads();
  }

  for (int idx = tid; idx < HP1 * HP1; idx += 256) {
    int i = idx / HP1, j = idx % HP1;
    out[OFF_WS + (t * HP1 + i) * HP1 + j] = G[i][41 + j];
  }
  if (tid < HP1) {
    float s = 0.f;
    for (int j = 0; j < HP1; ++j) s += G[tid][41 + j] * bs[j];
    float w = zetaExp * s;
    wmv[tid] = w;
    out[OFF_WM + t * HP1 + tid] = w;
  }
  __syncthreads();
  float lt2 = 0.f;
  for (int idx = tid; idx < HP1 * HP1; idx += 256) {
    int i = idx / HP1, j = idx % HP1;
    lt2 += As[i][j] * G[i][41 + j];
  }
  red[tid] = lt2; __syncthreads();
  for (int s = 128; s > 0; s >>= 1) {
    if (tid < s) red[tid] += red[tid + s];
    __syncthreads();
  }
  float t2v = red[0];
  if (tid < HP1) {
    float w = wmv[tid];
    float aw = 0.f;
    for (int j = 0; j < HP1; ++j) aw += As[tid][j] * wmv[j];
    rowv[0][tid] = w * bs[tid];
    rowv[1][tid] = w * w;
    rowv[2][tid] = G[tid][41 + tid];
    rowv[3][tid] = w * aw;
  }
  __syncthreads();

  float sp = accv(part, AIDX(40, t, 40));
  float kap = 1000.f + sp;
  float syy = accv(part, AIDX(49, t, 49));

  if (tid == 0) {
    float wb = 0.f, wn = 0.f, trc = 0.f, quad = 0.f;
    for (int i = 0; i < HP1; ++i) {
      wb += rowv[0][i]; wn += rowv[1][i]; trc += rowv[2][i]; quad += rowv[3][i];
    }
    float t1 = syy - 2.f * wb + quad;
    out[OFF_BG1 + t] = 1.f + sp;
    float rest = 0.f;
    for (int u = t + 1; u < Tt; ++u) rest += accv(part, AIDX(40, u, 40));
    out[OFF_BG2 + t] = 1.f + rest;            // ALPHA_DP = 1
    out[OFF_KAPPA + t] = kap;
    out[OFF_NU + t] = sp + 100.f;
    out[OFF_ZA + t] = zetA[t] + 0.5f * (float)HP1;
    out[OFF_ZB + t] = zetB[t] + 0.5f * (wn + trc);
    out[OFF_EA + t] = epsA[t] + 0.5f * sp;
    out[OFF_EB + t] = epsB[t] + 0.5f * (t1 + t2v);
  }
  if (tid < Dd) {
    float m = accv(part, AIDX(40, t, 41 + tid)) / kap;
    mus[tid] = m;
    out[OFF_MU + tid * Tt + t] = m;
  }
  __syncthreads();
  if (tid < Dd * Dd) {
    int i = tid / Dd, j = tid % Dd;
    float S = accv(part, AIDX(41 + i, t, 41 + j));
    float v = (i == j ? 500.f : 0.f) + S - kap * mus[i] * mus[j];
    out[OFF_PSI + (i * Dd + j) * Tt + t] = v;
  }
}

extern "C" void kernel_launch(void* const* d_in, const int* in_sizes, int n_in,
                              void* d_out, int out_size, void* d_ws, size_t ws_size,
                              hipStream_t stream) {
  const float* Phi = (const float*)d_in[1];
  const float* Xd  = (const float*)d_in[2];
  const float* Yd  = (const float*)d_in[3];
  const float* W   = (const float*)d_in[4];
  const float* bb  = (const float*)d_in[5];
  const float* eA  = (const float*)d_in[6];
  const float* eB  = (const float*)d_in[7];
  const float* zA  = (const float*)d_in[8];
  const float* zB  = (const float*)d_in[9];
  float* out = (float*)d_out;
  float* ws  = (float*)d_ws;

  unsigned short* XeHi = (unsigned short*)(ws + XEH_OFF);
  unsigned short* XeLo = (unsigned short*)(ws + XEL_OFF);
  float* PhiT = ws + PHIT_OFF;
  float* part = ws + PART_OFF;
  float* P    = ws + P_OFF;

  // adapt chunk count to workspace (deterministic, graph-safe); target
  // grid ~= 241 blocks (one 8-wave block per CU, sp=13 K-steps each)
  long maxChunks = ((long)(ws_size / 4) - (long)P_OFF) / CSZ;
  if (maxChunks < 1) maxChunks = 1;
  long cap = maxChunks < 256 ? maxChunks : 256;
  long sp = (3125 + cap - 1) / cap;               // 32-k steps per chunk
  int CH = (int)(32 * sp);
  int KCe = (Nn + CH - 1) / CH;

  hipLaunchKernelGGL(elm_expand, dim3((Nn + 63) / 64), dim3(256), 0, stream,
                     Phi, Xd, Yd, W, bb, XeHi, XeLo, PhiT);
  hipLaunchKernelGGL(gram_mfma, dim3(KCe), dim3(512), 0, stream,
                     PhiT, XeHi, XeLo, P, CH);
  hipLaunchKernelGGL(reduce_a, dim3(52, 8), dim3(256), 0, stream,
                     (const float4*)P, KCe, (float4*)part);
  hipLaunchKernelGGL(finalize_kernel, dim3(Tt), dim3(256), 0, stream,
                     part, eA, eB, zA, zB, out);
}